// Round 8
// baseline (259.697 us; speedup 1.0000x reference)
//
#include <hip/hip_runtime.h>

typedef __bf16 bf16_t;
typedef bf16_t bf16x8 __attribute__((ext_vector_type(8)));
typedef unsigned short ushort8_t __attribute__((ext_vector_type(8)));
typedef unsigned short ushort4_t __attribute__((ext_vector_type(4)));
typedef float f32x4 __attribute__((ext_vector_type(4)));

__device__ __forceinline__ unsigned short f2bf(float f) {
    __bf16 h = (__bf16)f;
    return __builtin_bit_cast(unsigned short, h);
}
__device__ __forceinline__ float fast_tanh(float x) {
    float e2 = __expf(2.f * x);
    return 1.f - 2.f / (e2 + 1.f);
}
__device__ __forceinline__ float fast_sig(float x) {
    return 1.f / (1.f + __expf(-x));
}

// ---------------- K0: two 512x512 transpose+bf16 converts in one launch ----------------
__global__ void k0_wt2(const float* __restrict__ Wi2h, const float* __restrict__ Wh2h,
                       unsigned short* __restrict__ Wt, unsigned short* __restrict__ Wht) {
    __shared__ float tile[32][33];
    const float* W = blockIdx.z ? Wh2h : Wi2h;
    unsigned short* O = blockIdx.z ? Wht : Wt;
    int tx = threadIdx.x, ty = threadIdx.y;
    int bx = blockIdx.x, by = blockIdx.y;
#pragma unroll
    for (int j = 0; j < 4; ++j) {
        int r = by * 32 + ty + j * 8;
        int c = bx * 32 + tx;
        tile[ty + j * 8][tx] = W[r * 512 + c];
    }
    __syncthreads();
#pragma unroll
    for (int j = 0; j < 4; ++j) {
        int h = bx * 32 + ty + j * 8;
        int d = by * 32 + tx;
        O[h * 512 + d] = f2bf(tile[tx][ty + j * 8]);
    }
}

// ---------------- K1x: bf16 convert ----------------
__global__ void k1x_conv(const float* __restrict__ src, unsigned short* __restrict__ dst) {
    int i = blockIdx.x * 256 + threadIdx.x;
    float4 f = ((const float4*)src)[i];
    ushort4_t u;
    u[0] = f2bf(f.x); u[1] = f2bf(f.y); u[2] = f2bf(f.z); u[3] = f2bf(f.w);
    ((ushort4_t*)dst)[i] = u;
}

// ---------------- K1m: h_proj = prev_h @ Wh2h + bh2h via MFMA ----------------
__global__ void k1m_hproj(const unsigned short* __restrict__ ph_bf,
                          const unsigned short* __restrict__ Wht,
                          const float* __restrict__ bh2h,
                          float* __restrict__ h_proj) {
    int tid = threadIdx.x;
    int wave = tid >> 6, lane = tid & 63;
    int l15 = lane & 15, g = lane >> 4;
    int h0 = blockIdx.x * 64 + wave * 16;
    int m0 = blockIdx.y * 32;

    f32x4 acc[2];
    acc[0] = (f32x4){0.f, 0.f, 0.f, 0.f};
    acc[1] = (f32x4){0.f, 0.f, 0.f, 0.f};

    const unsigned short* abase = ph_bf + (size_t)(m0 + l15) * 512 + g * 8;
    const unsigned short* bbase = Wht + (size_t)(h0 + l15) * 512 + g * 8;
#pragma unroll
    for (int j = 0; j < 16; ++j) {
        bf16x8 bf = __builtin_bit_cast(bf16x8, *(const ushort8_t*)(bbase + j * 32));
        bf16x8 a0 = __builtin_bit_cast(bf16x8, *(const ushort8_t*)(abase + j * 32));
        bf16x8 a1 = __builtin_bit_cast(bf16x8, *(const ushort8_t*)(abase + 16 * 512 + j * 32));
        acc[0] = __builtin_amdgcn_mfma_f32_16x16x32_bf16(a0, bf, acc[0], 0, 0, 0);
        acc[1] = __builtin_amdgcn_mfma_f32_16x16x32_bf16(a1, bf, acc[1], 0, 0, 0);
    }
    int h = h0 + l15;
    float bias = bh2h[h];
#pragma unroll
    for (int mf = 0; mf < 2; ++mf)
#pragma unroll
        for (int r = 0; r < 4; ++r)
            h_proj[(size_t)(m0 + mf * 16 + g * 4 + r) * 512 + h] = acc[mf][r] + bias;
}

// ---------------- K2 v5: B-resident, A-streamed, barrier-free-K fused e-GEMM ----------------
// Grid 256 (1 block/CU): 64 m-groups x 4 nt, XCD-grouped so the 4 nt-blocks of one
// m-group share an XCD (A re-reads hit that XCD's L2). 512 threads = 8 waves (4wr x 2wc).
// B = Wt[n0..n0+128)[512] bf16 staged once into 128KB LDS (gload_lds w16, pre-swizzled
// source, proven r4/r5). ONE barrier total. Then 8 m-panels of 128 rows: A fragments
// stream fp32->regs with a depth-2 pipeline, cvt_pk to bf16, MFMA from LDS-B.
// Epilogue barrier-free: slot (nt*2+wc) of e_part8; k3 sums 8 slots.
__launch_bounds__(512, 1)
__global__ void k2v5_scores(const float* __restrict__ batch_H,
                            const unsigned short* __restrict__ Wt,   // [512 h][512 d] bf16
                            const float* __restrict__ h_proj,
                            const float* __restrict__ Wscore,
                            float* __restrict__ e_part8) {           // [8][65536]
    __shared__ __align__(16) char Bsw[128 * 1024];   // 131072 B

    int tid  = threadIdx.x;
    int wave = tid >> 6;
    int lane = tid & 63;
    int l15  = lane & 15, g = lane >> 4;
    int wr   = wave >> 1;        // 0..3: rows [wr*32, +32) in panel
    int wc   = wave & 1;         // 0..1: cols [wc*64, +64) in n-chunk

    // XCD-grouped decode: 4 nt-blocks of one m-group land on one XCD (bid%8 fixed)
    int xcd = blockIdx.x & 7, j = blockIdx.x >> 3;
    int mgroup = xcd * 8 + (j >> 2);    // 0..63
    int nt = j & 3;
    int n0 = nt * 128;

    // ---- B fill: 16 iters, each wave loads one full row (64 lanes x 16B = 1KB) ----
#pragma unroll
    for (int i = 0; i < 16; ++i) {
        int row = i * 8 + wave;                       // 0..127, wave-uniform
        int chS = lane ^ (row & 7);                   // pre-swizzled source chunk
        const unsigned short* src = Wt + (size_t)(n0 + row) * 512 + chS * 8;
        __builtin_amdgcn_global_load_lds(
            (const __attribute__((address_space(1))) void*)src,
            (__attribute__((address_space(3))) void*)(Bsw + row * 1024), 16, 0, 0);
    }
    __syncthreads();   // the ONLY barrier

    // per-block constants
    float wv[4];
#pragma unroll
    for (int nf = 0; nf < 4; ++nf)
        wv[nf] = Wscore[n0 + wc * 64 + nf * 16 + l15];

    int slot = nt * 2 + wc;

    float4 pf[2][2][2];   // [parity][mf][half] depth-2 A pipeline (statically indexed)

    // prologue: load (p=0, ks=0) and (p=0, ks=1)
    {
        int m00 = mgroup * 1024;    // (mgroup*8+0)*128
#pragma unroll
        for (int ks = 0; ks < 2; ++ks)
#pragma unroll
            for (int mf = 0; mf < 2; ++mf) {
                const float* ap = batch_H + (size_t)(m00 + wr * 32 + mf * 16 + l15) * 512 + ks * 32 + g * 8;
                pf[ks][mf][0] = *(const float4*)(ap);
                pf[ks][mf][1] = *(const float4*)(ap + 4);
            }
    }

    for (int p = 0; p < 8; ++p) {
        int m0 = (mgroup * 8 + p) * 128;
        int b  = (mgroup * 8 + p) >> 1;

        float hp[4];
#pragma unroll
        for (int nf = 0; nf < 4; ++nf)
            hp[nf] = h_proj[(size_t)b * 512 + n0 + wc * 64 + nf * 16 + l15];

        f32x4 acc[2][4];
#pragma unroll
        for (int mf = 0; mf < 2; ++mf)
#pragma unroll
            for (int nf = 0; nf < 4; ++nf)
                acc[mf][nf] = (f32x4){0.f, 0.f, 0.f, 0.f};

#pragma unroll
        for (int ks = 0; ks < 16; ++ks) {
            const int par = ks & 1;
            // convert staged fp32 -> bf16 frags
            bf16x8 af[2];
#pragma unroll
            for (int mf = 0; mf < 2; ++mf) {
                ushort8_t u;
                u[0] = f2bf(pf[par][mf][0].x); u[1] = f2bf(pf[par][mf][0].y);
                u[2] = f2bf(pf[par][mf][0].z); u[3] = f2bf(pf[par][mf][0].w);
                u[4] = f2bf(pf[par][mf][1].x); u[5] = f2bf(pf[par][mf][1].y);
                u[6] = f2bf(pf[par][mf][1].z); u[7] = f2bf(pf[par][mf][1].w);
                af[mf] = __builtin_bit_cast(bf16x8, u);
            }
            // issue loads for ks+2 (same panel) or next panel's ks-14
            if (ks < 14) {
#pragma unroll
                for (int mf = 0; mf < 2; ++mf) {
                    const float* ap = batch_H + (size_t)(m0 + wr * 32 + mf * 16 + l15) * 512 + (ks + 2) * 32 + g * 8;
                    pf[par][mf][0] = *(const float4*)(ap);
                    pf[par][mf][1] = *(const float4*)(ap + 4);
                }
            } else if (p < 7) {
#pragma unroll
                for (int mf = 0; mf < 2; ++mf) {
                    const float* ap = batch_H + (size_t)(m0 + 128 + wr * 32 + mf * 16 + l15) * 512 + (ks - 14) * 32 + g * 8;
                    pf[par][mf][0] = *(const float4*)(ap);
                    pf[par][mf][1] = *(const float4*)(ap + 4);
                }
            }
            // B frags from LDS (swizzled) + MFMA
#pragma unroll
            for (int nf = 0; nf < 4; ++nf) {
                int brow = wc * 64 + nf * 16 + l15;
                bf16x8 bfv = __builtin_bit_cast(bf16x8,
                    *(const ushort8_t*)(Bsw + brow * 1024 + (((ks * 4 + g) ^ (brow & 7)) << 4)));
#pragma unroll
                for (int mf = 0; mf < 2; ++mf)
                    acc[mf][nf] = __builtin_amdgcn_mfma_f32_16x16x32_bf16(
                        af[mf], bfv, acc[mf][nf], 0, 0, 0);
            }
        }

        // panel epilogue (barrier-free): fold tanh, shfl-reduce over l15, write slot
        float s[2][4];
#pragma unroll
        for (int mf = 0; mf < 2; ++mf)
#pragma unroll
            for (int r = 0; r < 4; ++r) s[mf][r] = 0.f;
#pragma unroll
        for (int nf = 0; nf < 4; ++nf) {
#pragma unroll
            for (int mf = 0; mf < 2; ++mf)
#pragma unroll
                for (int r = 0; r < 4; ++r)
                    s[mf][r] += wv[nf] * fast_tanh(acc[mf][nf][r] + hp[nf]);
        }
#pragma unroll
        for (int mf = 0; mf < 2; ++mf)
#pragma unroll
            for (int r = 0; r < 4; ++r) {
                float v = s[mf][r];
                v += __shfl_xor(v, 1);
                v += __shfl_xor(v, 2);
                v += __shfl_xor(v, 4);
                v += __shfl_xor(v, 8);
                s[mf][r] = v;
            }
        if (l15 == 0) {
#pragma unroll
            for (int mf = 0; mf < 2; ++mf) {
                f32x4 o = (f32x4){s[mf][0], s[mf][1], s[mf][2], s[mf][3]};
                *(f32x4*)(e_part8 + (size_t)slot * 65536 + m0 + wr * 32 + mf * 16 + g * 4) = o;
            }
        }
    }
}

// ---------------- K3: sum 8 e-partials + softmax over T per b ----------------
__global__ void k3_softmax(const float* __restrict__ e_part8, float* __restrict__ alpha_out) {
    __shared__ float red[4];
    int b = blockIdx.x, tid = threadIdx.x;
    int m = b * 256 + tid;
    float v = 0.f;
#pragma unroll
    for (int s = 0; s < 8; ++s) v += e_part8[(size_t)s * 65536 + m];
    float mx = v;
#pragma unroll
    for (int off = 32; off; off >>= 1) mx = fmaxf(mx, __shfl_xor(mx, off));
    if ((tid & 63) == 0) red[tid >> 6] = mx;
    __syncthreads();
    mx = fmaxf(fmaxf(red[0], red[1]), fmaxf(red[2], red[3]));
    float p = __expf(v - mx);
    __syncthreads();
    float sum = p;
#pragma unroll
    for (int off = 32; off; off >>= 1) sum += __shfl_xor(sum, off);
    if ((tid & 63) == 0) red[tid >> 6] = sum;
    __syncthreads();
    sum = red[0] + red[1] + red[2] + red[3];
    alpha_out[b * 256 + tid] = p / sum;
}

// ---------------- K4: context[b,d] = sum_t alpha[b,t] * batch_H[b,t,d] ----------------
__global__ void k4_context(const float* __restrict__ batch_H, const float* __restrict__ alpha,
                           float* __restrict__ context) {
    __shared__ float al[256];
    int b = blockIdx.y, dc = blockIdx.x, tid = threadIdx.x;
    al[tid] = alpha[b * 256 + tid];
    __syncthreads();
    int d = dc * 256 + tid;
    const float* bh = batch_H + (size_t)b * 256 * 512 + d;
    float acc = 0.f;
#pragma unroll 4
    for (int t = 0; t < 256; ++t)
        acc += al[t] * bh[(size_t)t * 512];
    context[b * 512 + d] = acc;
}

// ---------------- K5t: Wzt[n][k] = bf16([Wk;Uk][k][n]) ----------------
__global__ void k5t_wzt(const float* __restrict__ Wk, const float* __restrict__ Uk,
                        unsigned short* __restrict__ Wzt) {
    __shared__ float tile[32][33];
    int tx = threadIdx.x, ty = threadIdx.y;
    int bx = blockIdx.x;
    int by = blockIdx.y;
#pragma unroll
    for (int j = 0; j < 4; ++j) {
        int k = bx * 32 + ty + j * 8;
        int c = by * 32 + tx;
        float v = (k < 608) ? Wk[(size_t)k * 2048 + c] : Uk[(size_t)(k - 608) * 2048 + c];
        tile[ty + j * 8][tx] = v;
    }
    __syncthreads();
#pragma unroll
    for (int j = 0; j < 4; ++j) {
        int n = by * 32 + ty + j * 8;
        int k = bx * 32 + tx;
        Wzt[(size_t)n * 1120 + k] = f2bf(tile[tx][ty + j * 8]);
    }
}

// ---------------- K5x: xb[b][k] = bf16([context;onehots;prev_h]) ----------------
__global__ void k5x_build(const float* __restrict__ context, const float* __restrict__ onehots,
                          const float* __restrict__ prev_h, unsigned short* __restrict__ xb) {
    int b = blockIdx.x, tid = threadIdx.x;
    for (int k = tid; k < 1120; k += 256) {
        float v;
        if (k < 512)      v = context[b * 512 + k];
        else if (k < 608) v = onehots[b * 96 + k - 512];
        else              v = prev_h[b * 512 + k - 608];
        xb[(size_t)b * 1120 + k] = f2bf(v);
    }
}

// ---------------- K5m: fused z-GEMM + LSTM gates ----------------
__launch_bounds__(256)
__global__ void k5m_fused(const unsigned short* __restrict__ xb,
                          const unsigned short* __restrict__ Wzt,
                          const float* __restrict__ bk,
                          const float* __restrict__ prev_c,
                          float* __restrict__ out) {
    __shared__ __align__(16) unsigned short Axs[32 * 232];

    int tid  = threadIdx.x;
    int wave = tid >> 6;
    int lane = tid & 63;
    int l15  = lane & 15;
    int g    = lane >> 4;
    int b0   = blockIdx.y * 32;
    int h0   = blockIdx.x * 64 + wave * 16;

    f32x4 acc[2][4];
#pragma unroll
    for (int mf = 0; mf < 2; ++mf)
#pragma unroll
        for (int gt = 0; gt < 4; ++gt)
            acc[mf][gt] = (f32x4){0.f, 0.f, 0.f, 0.f};

    const unsigned short* wbase = Wzt + (size_t)(h0 + l15) * 1120;

    for (int ks = 0; ks < 5; ++ks) {
        if (ks) __syncthreads();
        int kbase = ks * 224;
        for (int i = tid; i < 896; i += 256) {
            int row = i / 28;
            int c8  = (i % 28) * 8;
            *(ushort8_t*)(&Axs[row * 232 + c8]) =
                *(const ushort8_t*)(&xb[(size_t)(b0 + row) * 1120 + kbase + c8]);
        }
        __syncthreads();

        bf16x8 bcur[4], bnxt[4];
#pragma unroll
        for (int gt = 0; gt < 4; ++gt)
            bcur[gt] = __builtin_bit_cast(bf16x8,
                *(const ushort8_t*)(wbase + (size_t)gt * 512 * 1120 + kbase + g * 8));

#pragma unroll
        for (int kb = 0; kb < 7; ++kb) {
            if (kb < 6) {
                int kg = kbase + (kb + 1) * 32 + g * 8;
#pragma unroll
                for (int gt = 0; gt < 4; ++gt)
                    bnxt[gt] = __builtin_bit_cast(bf16x8,
                        *(const ushort8_t*)(wbase + (size_t)gt * 512 * 1120 + kg));
            }
            bf16x8 afrag[2];
#pragma unroll
            for (int mf = 0; mf < 2; ++mf)
                afrag[mf] = __builtin_bit_cast(bf16x8,
                    *(const ushort8_t*)(&Axs[(mf * 16 + l15) * 232 + kb * 32 + g * 8]));
#pragma unroll
            for (int gt = 0; gt < 4; ++gt)
#pragma unroll
                for (int mf = 0; mf < 2; ++mf)
                    acc[mf][gt] = __builtin_amdgcn_mfma_f32_16x16x32_bf16(
                        afrag[mf], bcur[gt], acc[mf][gt], 0, 0, 0);
#pragma unroll
            for (int gt = 0; gt < 4; ++gt) bcur[gt] = bnxt[gt];
        }
    }

    int h = h0 + l15;
    float bi = bk[h], bfv = bk[512 + h], bg = bk[1024 + h], bo = bk[1536 + h];
#pragma unroll
    for (int mf = 0; mf < 2; ++mf)
#pragma unroll
        for (int r = 0; r < 4; ++r) {
            int m = b0 + mf * 16 + g * 4 + r;
            float zi = acc[mf][0][r] + bi;
            float zf = acc[mf][1][r] + bfv;
            float zg = acc[mf][2][r] + bg;
            float zo = acc[mf][3][r] + bo;
            float c  = fast_sig(zf) * prev_c[m * 512 + h] + fast_sig(zi) * fast_tanh(zg);
            float hn = fast_sig(zo) * fast_tanh(c);
            out[m * 512 + h]          = hn;
            out[131072 + m * 512 + h] = c;
        }
}

extern "C" void kernel_launch(void* const* d_in, const int* in_sizes, int n_in,
                              void* d_out, int out_size, void* d_ws, size_t ws_size,
                              hipStream_t stream) {
    (void)in_sizes; (void)n_in; (void)out_size; (void)ws_size;
    const float* prev_h  = (const float*)d_in[0];
    const float* prev_c  = (const float*)d_in[1];
    const float* batch_H = (const float*)d_in[2];
    const float* onehots = (const float*)d_in[3];
    const float* Wi2h    = (const float*)d_in[4];
    const float* Wh2h    = (const float*)d_in[5];
    const float* bh2h    = (const float*)d_in[6];
    const float* Wscore  = (const float*)d_in[7];
    const float* Wk      = (const float*)d_in[8];
    const float* Uk      = (const float*)d_in[9];
    const float* bk      = (const float*)d_in[10];
    float* out = (float*)d_out;
    float* alpha = out + 262144;

    char* ws = (char*)d_ws;
    // Phase A (dead by k5t): [0, 3801088)
    unsigned short* Wt      = (unsigned short*)(ws + 0);        // 524288
    unsigned short* Wht     = (unsigned short*)(ws + 524288);   // 524288
    unsigned short* ph_bf   = (unsigned short*)(ws + 1048576);  // 262144
    float*          h_proj  = (float*)(ws + 1310720);           // 524288
    float*          e_part8 = (float*)(ws + 1835008);           // 2097152, ends 3932160
    // Phase B: Wzt overwrites [0, 4587520) after Phase A is dead
    unsigned short* Wzt     = (unsigned short*)(ws + 0);        // 4587520
    unsigned short* xb      = (unsigned short*)(ws + 4587520);  // 573440, ends 5160960
    float*          context = (float*)(ws + 5160960);           // 524288, ends 5685248

    k0_wt2     <<<dim3(16, 16, 2), dim3(32, 8), 0, stream>>>(Wi2h, Wh2h, Wt, Wht);
    k1x_conv   <<<128, 256, 0, stream>>>(prev_h, ph_bf);
    k1m_hproj  <<<dim3(8, 8), 256, 0, stream>>>(ph_bf, Wht, bh2h, h_proj);
    k2v5_scores<<<256, 512, 0, stream>>>(batch_H, Wt, h_proj, Wscore, e_part8);
    k3_softmax <<<256, 256, 0, stream>>>(e_part8, alpha);
    k4_context <<<dim3(2, 256), 256, 0, stream>>>(batch_H, alpha, context);
    k5t_wzt    <<<dim3(35, 64), dim3(32, 8), 0, stream>>>(Wk, Uk, Wzt);
    k5x_build  <<<256, 256, 0, stream>>>(context, onehots, prev_h, xb);
    k5m_fused  <<<dim3(8, 8), 256, 0, stream>>>(xb, Wzt, bk, prev_c, out);
}

// Round 9
// 166.507 us; speedup vs baseline: 1.5597x; 1.5597x over previous
//
#include <hip/hip_runtime.h>

typedef __bf16 bf16_t;
typedef bf16_t bf16x8 __attribute__((ext_vector_type(8)));
typedef unsigned short ushort8_t __attribute__((ext_vector_type(8)));
typedef unsigned short ushort4_t __attribute__((ext_vector_type(4)));
typedef float f32x4 __attribute__((ext_vector_type(4)));

__device__ __forceinline__ unsigned short f2bf(float f) {
    __bf16 h = (__bf16)f;
    return __builtin_bit_cast(unsigned short, h);
}
__device__ __forceinline__ float fast_tanh(float x) {
    float e2 = __expf(2.f * x);
    return 1.f - 2.f / (e2 + 1.f);
}
__device__ __forceinline__ float fast_sig(float x) {
    return 1.f / (1.f + __expf(-x));
}

// ---------------- K0: two 512x512 transpose+bf16 converts in one launch ----------------
__global__ void k0_wt2(const float* __restrict__ Wi2h, const float* __restrict__ Wh2h,
                       unsigned short* __restrict__ Wt, unsigned short* __restrict__ Wht) {
    __shared__ float tile[32][33];
    const float* W = blockIdx.z ? Wh2h : Wi2h;
    unsigned short* O = blockIdx.z ? Wht : Wt;
    int tx = threadIdx.x, ty = threadIdx.y;
    int bx = blockIdx.x, by = blockIdx.y;
#pragma unroll
    for (int j = 0; j < 4; ++j) {
        int r = by * 32 + ty + j * 8;
        int c = bx * 32 + tx;
        tile[ty + j * 8][tx] = W[r * 512 + c];
    }
    __syncthreads();
#pragma unroll
    for (int j = 0; j < 4; ++j) {
        int h = bx * 32 + ty + j * 8;
        int d = by * 32 + tx;
        O[h * 512 + d] = f2bf(tile[tx][ty + j * 8]);
    }
}

// ---------------- K1x: bf16 convert (float4 -> ushort4) ----------------
__global__ void k1x_conv(const float* __restrict__ src, unsigned short* __restrict__ dst) {
    int i = blockIdx.x * 256 + threadIdx.x;
    float4 f = ((const float4*)src)[i];
    ushort4_t u;
    u[0] = f2bf(f.x); u[1] = f2bf(f.y); u[2] = f2bf(f.z); u[3] = f2bf(f.w);
    ((ushort4_t*)dst)[i] = u;
}

// ---------------- K1m: h_proj = prev_h @ Wh2h + bh2h via MFMA ----------------
__global__ void k1m_hproj(const unsigned short* __restrict__ ph_bf,
                          const unsigned short* __restrict__ Wht,
                          const float* __restrict__ bh2h,
                          float* __restrict__ h_proj) {
    int tid = threadIdx.x;
    int wave = tid >> 6, lane = tid & 63;
    int l15 = lane & 15, g = lane >> 4;
    int h0 = blockIdx.x * 64 + wave * 16;
    int m0 = blockIdx.y * 32;

    f32x4 acc[2];
    acc[0] = (f32x4){0.f, 0.f, 0.f, 0.f};
    acc[1] = (f32x4){0.f, 0.f, 0.f, 0.f};

    const unsigned short* abase = ph_bf + (size_t)(m0 + l15) * 512 + g * 8;
    const unsigned short* bbase = Wht + (size_t)(h0 + l15) * 512 + g * 8;
#pragma unroll
    for (int j = 0; j < 16; ++j) {
        bf16x8 bf = __builtin_bit_cast(bf16x8, *(const ushort8_t*)(bbase + j * 32));
        bf16x8 a0 = __builtin_bit_cast(bf16x8, *(const ushort8_t*)(abase + j * 32));
        bf16x8 a1 = __builtin_bit_cast(bf16x8, *(const ushort8_t*)(abase + 16 * 512 + j * 32));
        acc[0] = __builtin_amdgcn_mfma_f32_16x16x32_bf16(a0, bf, acc[0], 0, 0, 0);
        acc[1] = __builtin_amdgcn_mfma_f32_16x16x32_bf16(a1, bf, acc[1], 0, 0, 0);
    }
    int h = h0 + l15;
    float bias = bh2h[h];
#pragma unroll
    for (int mf = 0; mf < 2; ++mf)
#pragma unroll
        for (int r = 0; r < 4; ++r)
            h_proj[(size_t)(m0 + mf * 16 + g * 4 + r) * 512 + h] = acc[mf][r] + bias;
}

// ---------------- K2 (r4-proven m97 structure, occupancy 4 blocks/CU) ----------------
// Grid 2048 = 512 m-tiles x 4 n-tiles (XCD-swizzled). 256 threads = 4 waves (2x2).
// Block tile 128x128, K=512, BK=64; B via global_load_lds w16 pre-swizzled source;
// A reg-staged fp32->bf16 (native cvt), swizzled ds_write. LDS 34.8KB -> 4 blocks/CU.
__launch_bounds__(256, 4)
__global__ void k2_scores(const float* __restrict__ batch_H,
                          const unsigned short* __restrict__ Wt,
                          const float* __restrict__ h_proj,
                          const float* __restrict__ Wscore,
                          float* __restrict__ e_part) {
    __shared__ __align__(16) unsigned short Alds[8192];
    __shared__ __align__(16) unsigned short Blds[8192];
    __shared__ float hp_s[128];
    __shared__ float wsc_s[128];
    __shared__ float e_red[4][64];

    int tid = threadIdx.x;
    int wg = (blockIdx.x & 7) * 256 + (blockIdx.x >> 3);
    int mt = wg >> 2, nt = wg & 3;
    int m0 = mt * 128, n0 = nt * 128;
    int b  = m0 >> 8;

    if (tid < 128) hp_s[tid] = h_proj[(size_t)b * 512 + n0 + tid];
    else           wsc_s[tid - 128] = Wscore[n0 + tid - 128];

    int wave = tid >> 6;
    int lane = tid & 63;
    int wr = wave >> 1;
    int wc = wave & 1;
    int l15 = lane & 15, g = lane >> 4;
    int bchunk = ((lane & 7) ^ (lane >> 3)) << 3;
    int brow_l = lane >> 3;

    f32x4 acc[4][4];
#pragma unroll
    for (int mf = 0; mf < 4; ++mf)
#pragma unroll
        for (int nf = 0; nf < 4; ++nf)
            acc[mf][nf] = (f32x4){0.f, 0.f, 0.f, 0.f};

    for (int ks = 0; ks < 8; ++ks) {
        __syncthreads();
        int kbase = ks * 64;
#pragma unroll
        for (int i = 0; i < 4; ++i) {
            int q = wave * 4 + i;
            int row = q * 8 + brow_l;
            const unsigned short* gsrc = Wt + (size_t)(n0 + row) * 512 + kbase + bchunk;
            __builtin_amdgcn_global_load_lds(
                (const __attribute__((address_space(1))) void*)gsrc,
                (__attribute__((address_space(3))) void*)&Blds[q * 512], 16, 0, 0);
        }
        float4 av[8];
#pragma unroll
        for (int j = 0; j < 8; ++j) {
            int idx = j * 256 + tid;
            int r = idx >> 4, c4 = idx & 15;
            av[j] = *(const float4*)(batch_H + (size_t)(m0 + r) * 512 + kbase + c4 * 4);
        }
#pragma unroll
        for (int j = 0; j < 8; ++j) {
            int idx = j * 256 + tid;
            int r = idx >> 4, c4 = idx & 15;
            ushort4_t u;
            u[0] = f2bf(av[j].x); u[1] = f2bf(av[j].y);
            u[2] = f2bf(av[j].z); u[3] = f2bf(av[j].w);
            int boff = r * 128 + ((((c4 >> 1) ^ (r & 7)) << 4) | ((c4 & 1) << 3));
            *(ushort4_t*)((char*)Alds + boff) = u;
        }
        __syncthreads();
#pragma unroll
        for (int kk = 0; kk < 2; ++kk) {
            bf16x8 af[4], bfr[4];
#pragma unroll
            for (int mf = 0; mf < 4; ++mf) {
                int row = wr * 64 + mf * 16 + l15;
                int boff = row * 128 + ((((kk * 4 + g) ^ (l15 & 7))) << 4);
                af[mf] = __builtin_bit_cast(bf16x8, *(const ushort8_t*)((char*)Alds + boff));
            }
#pragma unroll
            for (int nf = 0; nf < 4; ++nf) {
                int row = wc * 64 + nf * 16 + l15;
                int boff = row * 128 + ((((kk * 4 + g) ^ (l15 & 7))) << 4);
                bfr[nf] = __builtin_bit_cast(bf16x8, *(const ushort8_t*)((char*)Blds + boff));
            }
#pragma unroll
            for (int nf = 0; nf < 4; ++nf)
#pragma unroll
                for (int mf = 0; mf < 4; ++mf)
                    acc[mf][nf] = __builtin_amdgcn_mfma_f32_16x16x32_bf16(
                        af[mf], bfr[nf], acc[mf][nf], 0, 0, 0);
        }
    }

    float s[4][4];
#pragma unroll
    for (int mf = 0; mf < 4; ++mf)
#pragma unroll
        for (int r = 0; r < 4; ++r) s[mf][r] = 0.f;

#pragma unroll
    for (int nf = 0; nf < 4; ++nf) {
        int nl = wc * 64 + nf * 16 + l15;
        float hpv = hp_s[nl], wv = wsc_s[nl];
#pragma unroll
        for (int mf = 0; mf < 4; ++mf)
#pragma unroll
            for (int r = 0; r < 4; ++r)
                s[mf][r] += wv * fast_tanh(acc[mf][nf][r] + hpv);
    }
#pragma unroll
    for (int mf = 0; mf < 4; ++mf)
#pragma unroll
        for (int r = 0; r < 4; ++r) {
            float v = s[mf][r];
            v += __shfl_xor(v, 1);
            v += __shfl_xor(v, 2);
            v += __shfl_xor(v, 4);
            v += __shfl_xor(v, 8);
            s[mf][r] = v;
        }
    if (l15 == 0) {
#pragma unroll
        for (int mf = 0; mf < 4; ++mf)
#pragma unroll
            for (int r = 0; r < 4; ++r)
                e_red[wave][mf * 16 + g * 4 + r] = s[mf][r];
    }
    __syncthreads();
    if (tid < 128) {
        int wrr = tid >> 6, i64 = tid & 63;
        float v = e_red[wrr * 2 + 0][i64] + e_red[wrr * 2 + 1][i64];
        e_part[(size_t)nt * 65536 + m0 + tid] = v;
    }
}

// ---------------- K3: sum 4 e-partials + softmax over T per b ----------------
__global__ void k3_softmax(const float* __restrict__ e_part, float* __restrict__ alpha_out) {
    __shared__ float red[4];
    int b = blockIdx.x, tid = threadIdx.x;
    int m = b * 256 + tid;
    float v = e_part[m] + e_part[65536 + m] + e_part[131072 + m] + e_part[196608 + m];
    float mx = v;
#pragma unroll
    for (int off = 32; off; off >>= 1) mx = fmaxf(mx, __shfl_xor(mx, off));
    if ((tid & 63) == 0) red[tid >> 6] = mx;
    __syncthreads();
    mx = fmaxf(fmaxf(red[0], red[1]), fmaxf(red[2], red[3]));
    float p = __expf(v - mx);
    __syncthreads();
    float sum = p;
#pragma unroll
    for (int off = 32; off; off >>= 1) sum += __shfl_xor(sum, off);
    if ((tid & 63) == 0) red[tid >> 6] = sum;
    __syncthreads();
    sum = red[0] + red[1] + red[2] + red[3];
    alpha_out[b * 256 + tid] = p / sum;
}

// ---------------- K4: context[b,d] = sum_t alpha[b,t] * batch_H[b,t,d] ----------------
__global__ void k4_context(const float* __restrict__ batch_H, const float* __restrict__ alpha,
                           float* __restrict__ context) {
    __shared__ float al[256];
    int b = blockIdx.y, dc = blockIdx.x, tid = threadIdx.x;
    al[tid] = alpha[b * 256 + tid];
    __syncthreads();
    int d = dc * 256 + tid;
    const float* bh = batch_H + (size_t)b * 256 * 512 + d;
    float acc = 0.f;
#pragma unroll 4
    for (int t = 0; t < 256; ++t)
        acc += al[t] * bh[(size_t)t * 512];
    context[b * 512 + d] = acc;
}

// ---------------- K5t: Wzt[n][k] = bf16([Wk;Uk][k][n]) ----------------
__global__ void k5t_wzt(const float* __restrict__ Wk, const float* __restrict__ Uk,
                        unsigned short* __restrict__ Wzt) {
    __shared__ float tile[32][33];
    int tx = threadIdx.x, ty = threadIdx.y;
    int bx = blockIdx.x;
    int by = blockIdx.y;
#pragma unroll
    for (int j = 0; j < 4; ++j) {
        int k = bx * 32 + ty + j * 8;
        int c = by * 32 + tx;
        float v = (k < 608) ? Wk[(size_t)k * 2048 + c] : Uk[(size_t)(k - 608) * 2048 + c];
        tile[ty + j * 8][tx] = v;
    }
    __syncthreads();
#pragma unroll
    for (int j = 0; j < 4; ++j) {
        int n = by * 32 + ty + j * 8;
        int k = bx * 32 + tx;
        Wzt[(size_t)n * 1120 + k] = f2bf(tile[tx][ty + j * 8]);
    }
}

// ---------------- K5x: xb[b][k] = bf16([context;onehots;prev_h]) ----------------
__global__ void k5x_build(const float* __restrict__ context, const float* __restrict__ onehots,
                          const float* __restrict__ prev_h, unsigned short* __restrict__ xb) {
    int b = blockIdx.x, tid = threadIdx.x;
    for (int k = tid; k < 1120; k += 256) {
        float v;
        if (k < 512)      v = context[b * 512 + k];
        else if (k < 608) v = onehots[b * 96 + k - 512];
        else              v = prev_h[b * 512 + k - 608];
        xb[(size_t)b * 1120 + k] = f2bf(v);
    }
}

// ---------------- K5m: fused z-GEMM + LSTM gates ----------------
__launch_bounds__(256)
__global__ void k5m_fused(const unsigned short* __restrict__ xb,
                          const unsigned short* __restrict__ Wzt,
                          const float* __restrict__ bk,
                          const float* __restrict__ prev_c,
                          float* __restrict__ out) {
    __shared__ __align__(16) unsigned short Axs[32 * 232];

    int tid  = threadIdx.x;
    int wave = tid >> 6;
    int lane = tid & 63;
    int l15  = lane & 15;
    int g    = lane >> 4;
    int b0   = blockIdx.y * 32;
    int h0   = blockIdx.x * 64 + wave * 16;

    f32x4 acc[2][4];
#pragma unroll
    for (int mf = 0; mf < 2; ++mf)
#pragma unroll
        for (int gt = 0; gt < 4; ++gt)
            acc[mf][gt] = (f32x4){0.f, 0.f, 0.f, 0.f};

    const unsigned short* wbase = Wzt + (size_t)(h0 + l15) * 1120;

    for (int ks = 0; ks < 5; ++ks) {
        if (ks) __syncthreads();
        int kbase = ks * 224;
        for (int i = tid; i < 896; i += 256) {
            int row = i / 28;
            int c8  = (i % 28) * 8;
            *(ushort8_t*)(&Axs[row * 232 + c8]) =
                *(const ushort8_t*)(&xb[(size_t)(b0 + row) * 1120 + kbase + c8]);
        }
        __syncthreads();

        bf16x8 bcur[4], bnxt[4];
#pragma unroll
        for (int gt = 0; gt < 4; ++gt)
            bcur[gt] = __builtin_bit_cast(bf16x8,
                *(const ushort8_t*)(wbase + (size_t)gt * 512 * 1120 + kbase + g * 8));

#pragma unroll
        for (int kb = 0; kb < 7; ++kb) {
            if (kb < 6) {
                int kg = kbase + (kb + 1) * 32 + g * 8;
#pragma unroll
                for (int gt = 0; gt < 4; ++gt)
                    bnxt[gt] = __builtin_bit_cast(bf16x8,
                        *(const ushort8_t*)(wbase + (size_t)gt * 512 * 1120 + kg));
            }
            bf16x8 afrag[2];
#pragma unroll
            for (int mf = 0; mf < 2; ++mf)
                afrag[mf] = __builtin_bit_cast(bf16x8,
                    *(const ushort8_t*)(&Axs[(mf * 16 + l15) * 232 + kb * 32 + g * 8]));
#pragma unroll
            for (int gt = 0; gt < 4; ++gt)
#pragma unroll
                for (int mf = 0; mf < 2; ++mf)
                    acc[mf][gt] = __builtin_amdgcn_mfma_f32_16x16x32_bf16(
                        afrag[mf], bcur[gt], acc[mf][gt], 0, 0, 0);
#pragma unroll
            for (int gt = 0; gt < 4; ++gt) bcur[gt] = bnxt[gt];
        }
    }

    int h = h0 + l15;
    float bi = bk[h], bfv = bk[512 + h], bg = bk[1024 + h], bo = bk[1536 + h];
#pragma unroll
    for (int mf = 0; mf < 2; ++mf)
#pragma unroll
        for (int r = 0; r < 4; ++r) {
            int m = b0 + mf * 16 + g * 4 + r;
            float zi = acc[mf][0][r] + bi;
            float zf = acc[mf][1][r] + bfv;
            float zg = acc[mf][2][r] + bg;
            float zo = acc[mf][3][r] + bo;
            float c  = fast_sig(zf) * prev_c[m * 512 + h] + fast_sig(zi) * fast_tanh(zg);
            float hn = fast_sig(zo) * fast_tanh(c);
            out[m * 512 + h]          = hn;
            out[131072 + m * 512 + h] = c;
        }
}

extern "C" void kernel_launch(void* const* d_in, const int* in_sizes, int n_in,
                              void* d_out, int out_size, void* d_ws, size_t ws_size,
                              hipStream_t stream) {
    (void)in_sizes; (void)n_in; (void)out_size; (void)ws_size;
    const float* prev_h  = (const float*)d_in[0];
    const float* prev_c  = (const float*)d_in[1];
    const float* batch_H = (const float*)d_in[2];
    const float* onehots = (const float*)d_in[3];
    const float* Wi2h    = (const float*)d_in[4];
    const float* Wh2h    = (const float*)d_in[5];
    const float* bh2h    = (const float*)d_in[6];
    const float* Wscore  = (const float*)d_in[7];
    const float* Wk      = (const float*)d_in[8];
    const float* Uk      = (const float*)d_in[9];
    const float* bk      = (const float*)d_in[10];
    float* out = (float*)d_out;
    float* alpha = out + 262144;

    char* ws = (char*)d_ws;
    // Phase A (dead by k5t): [0, 2883584)
    unsigned short* Wt     = (unsigned short*)(ws + 0);        // 524288
    unsigned short* Wht    = (unsigned short*)(ws + 524288);   // 524288
    unsigned short* ph_bf  = (unsigned short*)(ws + 1048576);  // 262144
    float*          h_proj = (float*)(ws + 1310720);           // 524288
    float*          e_part = (float*)(ws + 1835008);           // 1048576, ends 2883584
    // Phase B: Wzt overwrites [0, 4587520) after Phase A dead
    unsigned short* Wzt    = (unsigned short*)(ws + 0);        // 4587520
    unsigned short* xb     = (unsigned short*)(ws + 4587520);  // 573440, ends 5160960
    float*          context= (float*)(ws + 5160960);           // 524288, ends 5685248

    k0_wt2    <<<dim3(16, 16, 2), dim3(32, 8), 0, stream>>>(Wi2h, Wh2h, Wt, Wht);
    k1x_conv  <<<128, 256, 0, stream>>>(prev_h, ph_bf);
    k1m_hproj <<<dim3(8, 8), 256, 0, stream>>>(ph_bf, Wht, bh2h, h_proj);
    k2_scores <<<2048, 256, 0, stream>>>(batch_H, Wt, h_proj, Wscore, e_part);
    k3_softmax<<<256, 256, 0, stream>>>(e_part, alpha);
    k4_context<<<dim3(2, 256), 256, 0, stream>>>(batch_H, alpha, context);
    k5t_wzt   <<<dim3(35, 64), dim3(32, 8), 0, stream>>>(Wk, Uk, Wzt);
    k5x_build <<<256, 256, 0, stream>>>(context, onehots, prev_h, xb);
    k5m_fused <<<dim3(8, 8), 256, 0, stream>>>(xb, Wzt, bk, prev_c, out);
}

// Round 10
// 152.356 us; speedup vs baseline: 1.7045x; 1.0929x over previous
//
#include <hip/hip_runtime.h>

typedef __bf16 bf16_t;
typedef bf16_t bf16x8 __attribute__((ext_vector_type(8)));
typedef unsigned short ushort8_t __attribute__((ext_vector_type(8)));
typedef unsigned short ushort4_t __attribute__((ext_vector_type(4)));
typedef float f32x4 __attribute__((ext_vector_type(4)));

__device__ __forceinline__ unsigned short f2bf(float f) {
    __bf16 h = (__bf16)f;
    return __builtin_bit_cast(unsigned short, h);
}
__device__ __forceinline__ float fast_tanh(float x) {
    float e2 = __expf(2.f * x);
    return 1.f - 2.f / (e2 + 1.f);
}
__device__ __forceinline__ float fast_sig(float x) {
    return 1.f / (1.f + __expf(-x));
}

// ---------------- K0: two 512x512 transpose+bf16 converts in one launch ----------------
__global__ void k0_wt2(const float* __restrict__ Wi2h, const float* __restrict__ Wh2h,
                       unsigned short* __restrict__ Wt, unsigned short* __restrict__ Wht) {
    __shared__ float tile[32][33];
    const float* W = blockIdx.z ? Wh2h : Wi2h;
    unsigned short* O = blockIdx.z ? Wht : Wt;
    int tx = threadIdx.x, ty = threadIdx.y;
    int bx = blockIdx.x, by = blockIdx.y;
#pragma unroll
    for (int j = 0; j < 4; ++j) {
        int r = by * 32 + ty + j * 8;
        int c = bx * 32 + tx;
        tile[ty + j * 8][tx] = W[r * 512 + c];
    }
    __syncthreads();
#pragma unroll
    for (int j = 0; j < 4; ++j) {
        int h = bx * 32 + ty + j * 8;
        int d = by * 32 + tx;
        O[h * 512 + d] = f2bf(tile[tx][ty + j * 8]);
    }
}

// ---------------- K1x: bf16 convert (float4 -> ushort4) ----------------
__global__ void k1x_conv(const float* __restrict__ src, unsigned short* __restrict__ dst) {
    int i = blockIdx.x * 256 + threadIdx.x;
    float4 f = ((const float4*)src)[i];
    ushort4_t u;
    u[0] = f2bf(f.x); u[1] = f2bf(f.y); u[2] = f2bf(f.z); u[3] = f2bf(f.w);
    ((ushort4_t*)dst)[i] = u;
}

// ---------------- K1m: h_proj = prev_h @ Wh2h + bh2h via MFMA ----------------
__global__ void k1m_hproj(const unsigned short* __restrict__ ph_bf,
                          const unsigned short* __restrict__ Wht,
                          const float* __restrict__ bh2h,
                          float* __restrict__ h_proj) {
    int tid = threadIdx.x;
    int wave = tid >> 6, lane = tid & 63;
    int l15 = lane & 15, g = lane >> 4;
    int h0 = blockIdx.x * 64 + wave * 16;
    int m0 = blockIdx.y * 32;

    f32x4 acc[2];
    acc[0] = (f32x4){0.f, 0.f, 0.f, 0.f};
    acc[1] = (f32x4){0.f, 0.f, 0.f, 0.f};

    const unsigned short* abase = ph_bf + (size_t)(m0 + l15) * 512 + g * 8;
    const unsigned short* bbase = Wht + (size_t)(h0 + l15) * 512 + g * 8;
#pragma unroll
    for (int j = 0; j < 16; ++j) {
        bf16x8 bf = __builtin_bit_cast(bf16x8, *(const ushort8_t*)(bbase + j * 32));
        bf16x8 a0 = __builtin_bit_cast(bf16x8, *(const ushort8_t*)(abase + j * 32));
        bf16x8 a1 = __builtin_bit_cast(bf16x8, *(const ushort8_t*)(abase + 16 * 512 + j * 32));
        acc[0] = __builtin_amdgcn_mfma_f32_16x16x32_bf16(a0, bf, acc[0], 0, 0, 0);
        acc[1] = __builtin_amdgcn_mfma_f32_16x16x32_bf16(a1, bf, acc[1], 0, 0, 0);
    }
    int h = h0 + l15;
    float bias = bh2h[h];
#pragma unroll
    for (int mf = 0; mf < 2; ++mf)
#pragma unroll
        for (int r = 0; r < 4; ++r)
            h_proj[(size_t)(m0 + mf * 16 + g * 4 + r) * 512 + h] = acc[mf][r] + bias;
}

// ---------------- K2 v6: r4 m97 structure + T3 2-phase pipeline ----------------
// Grid 2048 = 512 m-tiles x 4 n-tiles (XCD-swizzled). 256 threads = 4 waves (2x2).
// Block tile 128x128, K=512, BK=64 -> 8 slabs. Double-buffered A/B LDS (66 KB,
// 2 blocks/CU). Per slab: issue slab t+1 loads (B gload_lds + A fp32->regs) BEFORE
// computing slab t; cvt+ds_write A(t+1) after MFMA; one barrier per slab.
// Fragment math / swizzles identical to r4 (measured conflicts = 0).
__launch_bounds__(256, 2)
__global__ void k2_scores(const float* __restrict__ batch_H,
                          const unsigned short* __restrict__ Wt,
                          const float* __restrict__ h_proj,
                          const float* __restrict__ Wscore,
                          float* __restrict__ e_part) {
    __shared__ __align__(16) unsigned short Alds[2][8192];
    __shared__ __align__(16) unsigned short Blds[2][8192];
    __shared__ float hp_s[128];
    __shared__ float wsc_s[128];
    __shared__ float e_red[4][64];

    int tid = threadIdx.x;
    int wg = (blockIdx.x & 7) * 256 + (blockIdx.x >> 3);
    int mt = wg >> 2, nt = wg & 3;
    int m0 = mt * 128, n0 = nt * 128;
    int b  = m0 >> 8;

    if (tid < 128) hp_s[tid] = h_proj[(size_t)b * 512 + n0 + tid];
    else           wsc_s[tid - 128] = Wscore[n0 + tid - 128];

    int wave = tid >> 6;
    int lane = tid & 63;
    int wr = wave >> 1;
    int wc = wave & 1;
    int l15 = lane & 15, g = lane >> 4;
    int bchunk = ((lane & 7) ^ (lane >> 3)) << 3;   // pre-swizzled B source chunk
    int brow_l = lane >> 3;
    int ar  = tid >> 4;          // A stage: row base 0..15
    int ac4 = tid & 15;          // A stage: float4 col 0..15

    f32x4 acc[4][4];
#pragma unroll
    for (int mf = 0; mf < 4; ++mf)
#pragma unroll
        for (int nf = 0; nf < 4; ++nf)
            acc[mf][nf] = (f32x4){0.f, 0.f, 0.f, 0.f};

    float4 av[8];

    // ---- prologue: load + stage slab 0 into buffers 0 ----
#pragma unroll
    for (int i = 0; i < 4; ++i) {
        int q = wave * 4 + i, row = q * 8 + brow_l;
        const unsigned short* gsrc = Wt + (size_t)(n0 + row) * 512 + bchunk;
        __builtin_amdgcn_global_load_lds(
            (const __attribute__((address_space(1))) void*)gsrc,
            (__attribute__((address_space(3))) void*)&Blds[0][q * 512], 16, 0, 0);
    }
#pragma unroll
    for (int j = 0; j < 8; ++j)
        av[j] = *(const float4*)(batch_H + (size_t)(m0 + j * 16 + ar) * 512 + ac4 * 4);
#pragma unroll
    for (int j = 0; j < 8; ++j) {
        int r = j * 16 + ar;
        ushort4_t u;
        u[0] = f2bf(av[j].x); u[1] = f2bf(av[j].y);
        u[2] = f2bf(av[j].z); u[3] = f2bf(av[j].w);
        int boff = r * 128 + ((((ac4 >> 1) ^ (r & 7)) << 4) | ((ac4 & 1) << 3));
        *(ushort4_t*)((char*)&Alds[0][0] + boff) = u;
    }
    __syncthreads();

#pragma unroll
    for (int t = 0; t < 8; ++t) {
        const int cur = t & 1;
        // (1) issue next slab's loads early: they fly during this slab's compute
        if (t < 7) {
#pragma unroll
            for (int i = 0; i < 4; ++i) {
                int q = wave * 4 + i, row = q * 8 + brow_l;
                const unsigned short* gsrc =
                    Wt + (size_t)(n0 + row) * 512 + (t + 1) * 64 + bchunk;
                __builtin_amdgcn_global_load_lds(
                    (const __attribute__((address_space(1))) void*)gsrc,
                    (__attribute__((address_space(3))) void*)&Blds[cur ^ 1][q * 512], 16, 0, 0);
            }
#pragma unroll
            for (int j = 0; j < 8; ++j)
                av[j] = *(const float4*)(batch_H +
                    (size_t)(m0 + j * 16 + ar) * 512 + (t + 1) * 64 + ac4 * 4);
        }
        // (2) compute current slab from buf[cur]
#pragma unroll
        for (int kk = 0; kk < 2; ++kk) {
            bf16x8 af[4], bfr[4];
#pragma unroll
            for (int mf = 0; mf < 4; ++mf) {
                int row = wr * 64 + mf * 16 + l15;
                int boff = row * 128 + ((((kk * 4 + g) ^ (l15 & 7))) << 4);
                af[mf] = __builtin_bit_cast(bf16x8,
                    *(const ushort8_t*)((char*)&Alds[cur][0] + boff));
            }
#pragma unroll
            for (int nf = 0; nf < 4; ++nf) {
                int row = wc * 64 + nf * 16 + l15;
                int boff = row * 128 + ((((kk * 4 + g) ^ (l15 & 7))) << 4);
                bfr[nf] = __builtin_bit_cast(bf16x8,
                    *(const ushort8_t*)((char*)&Blds[cur][0] + boff));
            }
            __builtin_amdgcn_s_setprio(1);
#pragma unroll
            for (int nf = 0; nf < 4; ++nf)
#pragma unroll
                for (int mf = 0; mf < 4; ++mf)
                    acc[mf][nf] = __builtin_amdgcn_mfma_f32_16x16x32_bf16(
                        af[mf], bfr[nf], acc[mf][nf], 0, 0, 0);
            __builtin_amdgcn_s_setprio(0);
        }
        // (3) convert + write next A slab into buf^1 (waits only on av loads)
        if (t < 7) {
#pragma unroll
            for (int j = 0; j < 8; ++j) {
                int r = j * 16 + ar;
                ushort4_t u;
                u[0] = f2bf(av[j].x); u[1] = f2bf(av[j].y);
                u[2] = f2bf(av[j].z); u[3] = f2bf(av[j].w);
                int boff = r * 128 + ((((ac4 >> 1) ^ (r & 7)) << 4) | ((ac4 & 1) << 3));
                *(ushort4_t*)((char*)&Alds[cur ^ 1][0] + boff) = u;
            }
        }
        __syncthreads();
    }

    float s[4][4];
#pragma unroll
    for (int mf = 0; mf < 4; ++mf)
#pragma unroll
        for (int r = 0; r < 4; ++r) s[mf][r] = 0.f;

#pragma unroll
    for (int nf = 0; nf < 4; ++nf) {
        int nl = wc * 64 + nf * 16 + l15;
        float hpv = hp_s[nl], wv = wsc_s[nl];
#pragma unroll
        for (int mf = 0; mf < 4; ++mf)
#pragma unroll
            for (int r = 0; r < 4; ++r)
                s[mf][r] += wv * fast_tanh(acc[mf][nf][r] + hpv);
    }
#pragma unroll
    for (int mf = 0; mf < 4; ++mf)
#pragma unroll
        for (int r = 0; r < 4; ++r) {
            float v = s[mf][r];
            v += __shfl_xor(v, 1);
            v += __shfl_xor(v, 2);
            v += __shfl_xor(v, 4);
            v += __shfl_xor(v, 8);
            s[mf][r] = v;
        }
    if (l15 == 0) {
#pragma unroll
        for (int mf = 0; mf < 4; ++mf)
#pragma unroll
            for (int r = 0; r < 4; ++r)
                e_red[wave][mf * 16 + g * 4 + r] = s[mf][r];
    }
    __syncthreads();
    if (tid < 128) {
        int wrr = tid >> 6, i64 = tid & 63;
        float v = e_red[wrr * 2 + 0][i64] + e_red[wrr * 2 + 1][i64];
        e_part[(size_t)nt * 65536 + m0 + tid] = v;
    }
}

// ---------------- K3: sum 4 e-partials + softmax over T per b ----------------
__global__ void k3_softmax(const float* __restrict__ e_part, float* __restrict__ alpha_out) {
    __shared__ float red[4];
    int b = blockIdx.x, tid = threadIdx.x;
    int m = b * 256 + tid;
    float v = e_part[m] + e_part[65536 + m] + e_part[131072 + m] + e_part[196608 + m];
    float mx = v;
#pragma unroll
    for (int off = 32; off; off >>= 1) mx = fmaxf(mx, __shfl_xor(mx, off));
    if ((tid & 63) == 0) red[tid >> 6] = mx;
    __syncthreads();
    mx = fmaxf(fmaxf(red[0], red[1]), fmaxf(red[2], red[3]));
    float p = __expf(v - mx);
    __syncthreads();
    float sum = p;
#pragma unroll
    for (int off = 32; off; off >>= 1) sum += __shfl_xor(sum, off);
    if ((tid & 63) == 0) red[tid >> 6] = sum;
    __syncthreads();
    sum = red[0] + red[1] + red[2] + red[3];
    alpha_out[b * 256 + tid] = p / sum;
}

// ---------------- K4: context[b,d] = sum_t alpha[b,t] * batch_H[b,t,d] ----------------
__global__ void k4_context(const float* __restrict__ batch_H, const float* __restrict__ alpha,
                           float* __restrict__ context) {
    __shared__ float al[256];
    int b = blockIdx.y, dc = blockIdx.x, tid = threadIdx.x;
    al[tid] = alpha[b * 256 + tid];
    __syncthreads();
    int d = dc * 256 + tid;
    const float* bh = batch_H + (size_t)b * 256 * 512 + d;
    float acc = 0.f;
#pragma unroll 4
    for (int t = 0; t < 256; ++t)
        acc += al[t] * bh[(size_t)t * 512];
    context[b * 512 + d] = acc;
}

// ---------------- K5t: Wzt[n][k] = bf16([Wk;Uk][k][n]) ----------------
__global__ void k5t_wzt(const float* __restrict__ Wk, const float* __restrict__ Uk,
                        unsigned short* __restrict__ Wzt) {
    __shared__ float tile[32][33];
    int tx = threadIdx.x, ty = threadIdx.y;
    int bx = blockIdx.x;
    int by = blockIdx.y;
#pragma unroll
    for (int j = 0; j < 4; ++j) {
        int k = bx * 32 + ty + j * 8;
        int c = by * 32 + tx;
        float v = (k < 608) ? Wk[(size_t)k * 2048 + c] : Uk[(size_t)(k - 608) * 2048 + c];
        tile[ty + j * 8][tx] = v;
    }
    __syncthreads();
#pragma unroll
    for (int j = 0; j < 4; ++j) {
        int n = by * 32 + ty + j * 8;
        int k = bx * 32 + tx;
        Wzt[(size_t)n * 1120 + k] = f2bf(tile[tx][ty + j * 8]);
    }
}

// ---------------- K5x: xb[b][k] = bf16([context;onehots;prev_h]) ----------------
__global__ void k5x_build(const float* __restrict__ context, const float* __restrict__ onehots,
                          const float* __restrict__ prev_h, unsigned short* __restrict__ xb) {
    int b = blockIdx.x, tid = threadIdx.x;
    for (int k = tid; k < 1120; k += 256) {
        float v;
        if (k < 512)      v = context[b * 512 + k];
        else if (k < 608) v = onehots[b * 96 + k - 512];
        else              v = prev_h[b * 512 + k - 608];
        xb[(size_t)b * 1120 + k] = f2bf(v);
    }
}

// ---------------- K5m: fused z-GEMM + LSTM gates ----------------
__launch_bounds__(256)
__global__ void k5m_fused(const unsigned short* __restrict__ xb,
                          const unsigned short* __restrict__ Wzt,
                          const float* __restrict__ bk,
                          const float* __restrict__ prev_c,
                          float* __restrict__ out) {
    __shared__ __align__(16) unsigned short Axs[32 * 232];

    int tid  = threadIdx.x;
    int wave = tid >> 6;
    int lane = tid & 63;
    int l15  = lane & 15;
    int g    = lane >> 4;
    int b0   = blockIdx.y * 32;
    int h0   = blockIdx.x * 64 + wave * 16;

    f32x4 acc[2][4];
#pragma unroll
    for (int mf = 0; mf < 2; ++mf)
#pragma unroll
        for (int gt = 0; gt < 4; ++gt)
            acc[mf][gt] = (f32x4){0.f, 0.f, 0.f, 0.f};

    const unsigned short* wbase = Wzt + (size_t)(h0 + l15) * 1120;

    for (int ks = 0; ks < 5; ++ks) {
        if (ks) __syncthreads();
        int kbase = ks * 224;
        for (int i = tid; i < 896; i += 256) {
            int row = i / 28;
            int c8  = (i % 28) * 8;
            *(ushort8_t*)(&Axs[row * 232 + c8]) =
                *(const ushort8_t*)(&xb[(size_t)(b0 + row) * 1120 + kbase + c8]);
        }
        __syncthreads();

        bf16x8 bcur[4], bnxt[4];
#pragma unroll
        for (int gt = 0; gt < 4; ++gt)
            bcur[gt] = __builtin_bit_cast(bf16x8,
                *(const ushort8_t*)(wbase + (size_t)gt * 512 * 1120 + kbase + g * 8));

#pragma unroll
        for (int kb = 0; kb < 7; ++kb) {
            if (kb < 6) {
                int kg = kbase + (kb + 1) * 32 + g * 8;
#pragma unroll
                for (int gt = 0; gt < 4; ++gt)
                    bnxt[gt] = __builtin_bit_cast(bf16x8,
                        *(const ushort8_t*)(wbase + (size_t)gt * 512 * 1120 + kg));
            }
            bf16x8 afrag[2];
#pragma unroll
            for (int mf = 0; mf < 2; ++mf)
                afrag[mf] = __builtin_bit_cast(bf16x8,
                    *(const ushort8_t*)(&Axs[(mf * 16 + l15) * 232 + kb * 32 + g * 8]));
#pragma unroll
            for (int gt = 0; gt < 4; ++gt)
#pragma unroll
                for (int mf = 0; mf < 2; ++mf)
                    acc[mf][gt] = __builtin_amdgcn_mfma_f32_16x16x32_bf16(
                        afrag[mf], bcur[gt], acc[mf][gt], 0, 0, 0);
#pragma unroll
            for (int gt = 0; gt < 4; ++gt) bcur[gt] = bnxt[gt];
        }
    }

    int h = h0 + l15;
    float bi = bk[h], bfv = bk[512 + h], bg = bk[1024 + h], bo = bk[1536 + h];
#pragma unroll
    for (int mf = 0; mf < 2; ++mf)
#pragma unroll
        for (int r = 0; r < 4; ++r) {
            int m = b0 + mf * 16 + g * 4 + r;
            float zi = acc[mf][0][r] + bi;
            float zf = acc[mf][1][r] + bfv;
            float zg = acc[mf][2][r] + bg;
            float zo = acc[mf][3][r] + bo;
            float c  = fast_sig(zf) * prev_c[m * 512 + h] + fast_sig(zi) * fast_tanh(zg);
            float hn = fast_sig(zo) * fast_tanh(c);
            out[m * 512 + h]          = hn;
            out[131072 + m * 512 + h] = c;
        }
}

extern "C" void kernel_launch(void* const* d_in, const int* in_sizes, int n_in,
                              void* d_out, int out_size, void* d_ws, size_t ws_size,
                              hipStream_t stream) {
    (void)in_sizes; (void)n_in; (void)out_size; (void)ws_size;
    const float* prev_h  = (const float*)d_in[0];
    const float* prev_c  = (const float*)d_in[1];
    const float* batch_H = (const float*)d_in[2];
    const float* onehots = (const float*)d_in[3];
    const float* Wi2h    = (const float*)d_in[4];
    const float* Wh2h    = (const float*)d_in[5];
    const float* bh2h    = (const float*)d_in[6];
    const float* Wscore  = (const float*)d_in[7];
    const float* Wk      = (const float*)d_in[8];
    const float* Uk      = (const float*)d_in[9];
    const float* bk      = (const float*)d_in[10];
    float* out = (float*)d_out;
    float* alpha = out + 262144;

    char* ws = (char*)d_ws;
    // Phase A (dead by k5t): [0, 2883584)
    unsigned short* Wt     = (unsigned short*)(ws + 0);        // 524288
    unsigned short* Wht    = (unsigned short*)(ws + 524288);   // 524288
    unsigned short* ph_bf  = (unsigned short*)(ws + 1048576);  // 262144
    float*          h_proj = (float*)(ws + 1310720);           // 524288
    float*          e_part = (float*)(ws + 1835008);           // 1048576, ends 2883584
    // Phase B: Wzt overwrites [0, 4587520) after Phase A dead
    unsigned short* Wzt    = (unsigned short*)(ws + 0);        // 4587520
    unsigned short* xb     = (unsigned short*)(ws + 4587520);  // 573440, ends 5160960
    float*          context= (float*)(ws + 5160960);           // 524288, ends 5685248

    k0_wt2    <<<dim3(16, 16, 2), dim3(32, 8), 0, stream>>>(Wi2h, Wh2h, Wt, Wht);
    k1x_conv  <<<128, 256, 0, stream>>>(prev_h, ph_bf);
    k1m_hproj <<<dim3(8, 8), 256, 0, stream>>>(ph_bf, Wht, bh2h, h_proj);
    k2_scores <<<2048, 256, 0, stream>>>(batch_H, Wt, h_proj, Wscore, e_part);
    k3_softmax<<<256, 256, 0, stream>>>(e_part, alpha);
    k4_context<<<dim3(2, 256), 256, 0, stream>>>(batch_H, alpha, context);
    k5t_wzt   <<<dim3(35, 64), dim3(32, 8), 0, stream>>>(Wk, Uk, Wzt);
    k5x_build <<<256, 256, 0, stream>>>(context, onehots, prev_h, xb);
    k5m_fused <<<dim3(8, 8), 256, 0, stream>>>(xb, Wzt, bk, prev_c, out);
}